// Round 2
// baseline (261.635 us; speedup 1.0000x reference)
//
#include <hip/hip_runtime.h>

constexpr int HIDDEN = 1024;
constexpr int BATCH  = 32;
constexpr int SRC    = 4096;
constexpr int CHUNK  = 128;              // s-rows per fused block
constexpr int NCHUNK = SRC / CHUNK;      // 32

#define NEG_INF (-__builtin_inff())

// ---------- helpers ----------

__device__ __forceinline__ float wave_reduce_add(float v) {
    #pragma unroll
    for (int off = 32; off > 0; off >>= 1)
        v += __shfl_down(v, off, 64);
    return v;
}

__device__ __forceinline__ float wave_reduce_max(float v) {
    #pragma unroll
    for (int off = 32; off > 0; off >>= 1)
        v = fmaxf(v, __shfl_down(v, off, 64));
    return v;
}

// Dot of one 1024-f32 row (as float4[256]) against the wave's register-held
// query fragments (lane l holds q indices l, l+64, l+128, l+192 as float4).
__device__ __forceinline__ float row_dot(const float4* __restrict__ row, int lane,
                                         float4 q0, float4 q1, float4 q2, float4 q3) {
    float4 a = row[lane];
    float4 b = row[lane + 64];
    float4 c = row[lane + 128];
    float4 d = row[lane + 192];
    float acc = a.x*q0.x + a.y*q0.y + a.z*q0.z + a.w*q0.w
              + b.x*q1.x + b.y*q1.y + b.z*q1.z + b.w*q1.w
              + c.x*q2.x + c.y*q2.y + c.z*q2.z + c.w*q2.w
              + d.x*q3.x + d.y*q3.y + d.z*q3.z + d.w*q3.w;
    return wave_reduce_add(acc);
}

// ---------- K1: proj[b,o] = sum_i query[b,i] * W[o,i] ----------
// grid (BATCH, HIDDEN/256), block 256 (4 waves x 64 rows each)
__global__ __launch_bounds__(256) void k_proj(const float* __restrict__ query,
                                              const float* __restrict__ W,
                                              float* __restrict__ proj) {
    int b   = blockIdx.x;
    int oc  = blockIdx.y;
    int wid = threadIdx.x >> 6, lane = threadIdx.x & 63;
    const float4* q4 = (const float4*)(query + (size_t)b * HIDDEN);
    float4 q0 = q4[lane], q1 = q4[lane + 64], q2 = q4[lane + 128], q3 = q4[lane + 192];
    int o_base = oc * 256 + wid * 64;
    for (int i = 0; i < 64; ++i) {
        int o = o_base + i;
        const float4* wrow = (const float4*)(W + (size_t)o * HIDDEN);
        float s = row_dot(wrow, lane, q0, q1, q2, q3);
        if (lane == 0) proj[b * HIDDEN + o] = s;
    }
}

// ---------- K2 (fused): scores + local softmax stats + partial context ----------
// grid (BATCH, NCHUNK), block 256 (4 waves x 32 rows each).
// Writes: raw masked scores (for attn), lmax/lsum per chunk, unnormalized
// partial context  part = sum_{s in chunk} exp(score_s - lmax) * values[s,:].
__global__ __launch_bounds__(256) void k_fused(const float* __restrict__ keys,
                                               const float* __restrict__ values,
                                               const float* __restrict__ proj,
                                               const int* __restrict__ mask,
                                               float* __restrict__ scores_out,
                                               float* __restrict__ part,
                                               float* __restrict__ lmax_arr,
                                               float* __restrict__ lsum_arr) {
    int b   = blockIdx.x;
    int ch  = blockIdx.y;
    int tid = threadIdx.x;
    int wid = tid >> 6, lane = tid & 63;

    __shared__ float sc[CHUNK];   // masked scores for this chunk
    __shared__ float pw[CHUNK];   // exp(score - lmax)
    __shared__ float red[8];

    // --- phase 1: scores for 128 rows (keys chunk: 512 KB) ---
    const float4* p4 = (const float4*)(proj + (size_t)b * HIDDEN);
    float4 q0 = p4[lane], q1 = p4[lane + 64], q2 = p4[lane + 128], q3 = p4[lane + 192];
    int s0 = ch * CHUNK;
    for (int i = 0; i < 32; ++i) {
        int r = wid * 32 + i;
        int s = s0 + r;
        const float4* krow = (const float4*)(keys + ((size_t)b * SRC + s) * HIDDEN);
        float v = row_dot(krow, lane, q0, q1, q2, q3);
        if (lane == 0) {
            float m = mask[b * SRC + s] ? NEG_INF : v;
            sc[r] = m;
            scores_out[b * SRC + s] = m;
        }
    }
    __syncthreads();

    // --- phase 2: local max and exp-sum over the 128 scores ---
    float myv = (tid < CHUNK) ? sc[tid] : NEG_INF;
    float wm = wave_reduce_max(myv);
    if (lane == 0) red[wid] = wm;
    __syncthreads();
    float lmax = fmaxf(fmaxf(red[0], red[1]), fmaxf(red[2], red[3]));

    float pe = 0.f;
    if (tid < CHUNK) {
        pe = (lmax == NEG_INF) ? 0.f : __expf(myv - lmax);
        pw[tid] = pe;
    }
    float ws = wave_reduce_add(pe);
    if (lane == 0) red[4 + wid] = ws;
    __syncthreads();
    if (tid == 0) {
        lmax_arr[b * NCHUNK + ch] = lmax;
        lsum_arr[b * NCHUNK + ch] = red[4] + red[5] + red[6] + red[7];
    }

    // --- phase 3: partial context (values chunk: 512 KB) ---
    const float4* v4 = (const float4*)(values + ((size_t)b * SRC + s0) * HIDDEN);
    float4 acc = {0.f, 0.f, 0.f, 0.f};
    #pragma unroll 4
    for (int i = 0; i < CHUNK; ++i) {
        float  w = pw[i];
        float4 v = v4[(size_t)i * 256 + tid];
        acc.x += w * v.x; acc.y += w * v.y; acc.z += w * v.z; acc.w += w * v.w;
    }
    ((float4*)(part + (size_t)(b * NCHUNK + ch) * HIDDEN))[tid] = acc;
}

// ---------- K3: combine partials -> ctx, normalize scores -> attn ----------
// grid BATCH, block 256
__global__ __launch_bounds__(256) void k_combine(const float* __restrict__ part,
                                                 const float* __restrict__ lmax_arr,
                                                 const float* __restrict__ lsum_arr,
                                                 const float* __restrict__ scores,
                                                 float* __restrict__ ctx,
                                                 float* __restrict__ attn) {
    int b = blockIdx.x, tid = threadIdx.x;
    __shared__ float sm[NCHUNK], ss[NCHUNK];
    if (tid < NCHUNK) {
        sm[tid] = lmax_arr[b * NCHUNK + tid];
        ss[tid] = lsum_arr[b * NCHUNK + tid];
    }
    __syncthreads();

    float M = NEG_INF;
    #pragma unroll
    for (int c = 0; c < NCHUNK; ++c) M = fmaxf(M, sm[c]);
    float Sum = 0.f;
    #pragma unroll
    for (int c = 0; c < NCHUNK; ++c) {
        float e = (sm[c] == NEG_INF) ? 0.f : __expf(sm[c] - M);
        Sum += ss[c] * e;
    }
    float inv = 1.f / Sum;

    const float4* p4 = (const float4*)(part + (size_t)b * NCHUNK * HIDDEN);
    float4 acc = {0.f, 0.f, 0.f, 0.f};
    #pragma unroll
    for (int c = 0; c < NCHUNK; ++c) {
        float w = ((sm[c] == NEG_INF) ? 0.f : __expf(sm[c] - M)) * inv;
        float4 v = p4[c * 256 + tid];
        acc.x += w * v.x; acc.y += w * v.y; acc.z += w * v.z; acc.w += w * v.w;
    }
    ((float4*)(ctx + (size_t)b * HIDDEN))[tid] = acc;

    for (int j = tid; j < SRC; j += 256)
        attn[b * SRC + j] = __expf(scores[b * SRC + j] - M) * inv;
}

// ---------- launch ----------
extern "C" void kernel_launch(void* const* d_in, const int* in_sizes, int n_in,
                              void* d_out, int out_size, void* d_ws, size_t ws_size,
                              hipStream_t stream) {
    const float* query  = (const float*)d_in[0];
    const float* keys   = (const float*)d_in[1];
    const float* values = (const float*)d_in[2];
    const int*   mask   = (const int*)d_in[3];
    const float* W      = (const float*)d_in[4];

    float* ctx  = (float*)d_out;                  // (32, 1024)
    float* attn = (float*)d_out + BATCH * HIDDEN; // (32, 4096)

    float* proj   = (float*)d_ws;                       // 32768 f32
    float* scores = proj + BATCH * HIDDEN;              // 131072 f32
    float* part   = scores + BATCH * SRC;               // 32*32*1024 f32 = 4 MB
    float* lmax   = part + (size_t)BATCH * NCHUNK * HIDDEN; // 1024 f32
    float* lsum   = lmax + BATCH * NCHUNK;              // 1024 f32

    k_proj   <<<dim3(BATCH, HIDDEN / 256), 256, 0, stream>>>(query, W, proj);
    k_fused  <<<dim3(BATCH, NCHUNK),       256, 0, stream>>>(keys, values, proj, mask,
                                                             scores, part, lmax, lsum);
    k_combine<<<dim3(BATCH),               256, 0, stream>>>(part, lmax, lsum, scores,
                                                             ctx, attn);
}

// Round 5
// 213.922 us; speedup vs baseline: 1.2230x; 1.2230x over previous
//
#include <hip/hip_runtime.h>

constexpr int HIDDEN = 1024;
constexpr int BATCH  = 32;
constexpr int SRC    = 4096;
constexpr int CHUNK  = 128;              // s-rows per fused block
constexpr int NCHUNK = SRC / CHUNK;      // 32

#define NEG_INF (-__builtin_inff())

// ---------- helpers ----------

typedef float floatx4 __attribute__((ext_vector_type(4)));

__device__ __forceinline__ float4 ntload4(const float4* p) {
    floatx4 v = __builtin_nontemporal_load((const floatx4*)p);
    return make_float4(v.x, v.y, v.z, v.w);
}

__device__ __forceinline__ float wave_reduce_add(float v) {
    #pragma unroll
    for (int off = 32; off > 0; off >>= 1)
        v += __shfl_down(v, off, 64);
    return v;
}

__device__ __forceinline__ float wave_reduce_max(float v) {
    #pragma unroll
    for (int off = 32; off > 0; off >>= 1)
        v = fmaxf(v, __shfl_down(v, off, 64));
    return v;
}

__device__ __forceinline__ float dot16(float4 a, float4 b, float4 c, float4 d,
                                       float4 q0, float4 q1, float4 q2, float4 q3) {
    return a.x*q0.x + a.y*q0.y + a.z*q0.z + a.w*q0.w
         + b.x*q1.x + b.y*q1.y + b.z*q1.z + b.w*q1.w
         + c.x*q2.x + c.y*q2.y + c.z*q2.z + c.w*q2.w
         + d.x*q3.x + d.y*q3.y + d.z*q3.z + d.w*q3.w;
}

// ---------- K1: proj[b,o] = sum_i query[b,i] * W[o,i] ----------
// thread-per-(b,o), b minor: W loads wave-uniform (broadcast), W read once.
__global__ __launch_bounds__(256) void k_proj(const float* __restrict__ query,
                                              const float* __restrict__ W,
                                              float* __restrict__ proj) {
    int g = blockIdx.x * 256 + threadIdx.x;
    int b = g & (BATCH - 1);
    int o = g >> 5;
    const float4* W4 = (const float4*)(W + (size_t)o * HIDDEN);
    const float4* Q4 = (const float4*)(query + (size_t)b * HIDDEN);
    float4 acc = {0.f, 0.f, 0.f, 0.f};
    #pragma unroll 8
    for (int i = 0; i < HIDDEN / 4; ++i) {
        float4 w = W4[i];
        float4 q = Q4[i];
        acc.x += w.x * q.x; acc.y += w.y * q.y;
        acc.z += w.z * q.z; acc.w += w.w * q.w;
    }
    proj[(size_t)b * HIDDEN + o] = acc.x + acc.y + acc.z + acc.w;
}

// ---------- K2 (fused): scores + local softmax stats + partial context ----------
// grid (BATCH, NCHUNK), block 256 (4 waves x 32 rows each).
__global__ __launch_bounds__(256, 4) void k_fused(const float* __restrict__ keys,
                                                  const float* __restrict__ values,
                                                  const float* __restrict__ proj,
                                                  const int* __restrict__ mask,
                                                  float* __restrict__ scores_out,
                                                  float* __restrict__ part,
                                                  float* __restrict__ lmax_arr,
                                                  float* __restrict__ lsum_arr) {
    int b   = blockIdx.x;
    int ch  = blockIdx.y;
    int tid = threadIdx.x;
    int wid = tid >> 6, lane = tid & 63;

    __shared__ float sc[CHUNK];   // masked scores
    __shared__ float pw[CHUNK];   // exp(score - lmax)
    __shared__ float red[8];

    const float4* p4 = (const float4*)(proj + (size_t)b * HIDDEN);
    float4 q0 = p4[lane], q1 = p4[lane + 64], q2 = p4[lane + 128], q3 = p4[lane + 192];
    int s0    = ch * CHUNK;
    int rbase = wid * 32;

    // --- phase 1: scores, batched deferred reduction (16 rows at a time) ---
    #pragma unroll
    for (int h = 0; h < 2; ++h) {
        float acc[16];
        #pragma unroll 2
        for (int r = 0; r < 16; ++r) {
            int row = rbase + h * 16 + r;
            const float4* krow =
                (const float4*)(keys + ((size_t)b * SRC + s0 + row) * HIDDEN);
            float4 a = ntload4(krow + lane);
            float4 c = ntload4(krow + lane + 64);
            float4 d = ntload4(krow + lane + 128);
            float4 e = ntload4(krow + lane + 192);
            acc[r] = dot16(a, c, d, e, q0, q1, q2, q3);
        }
        #pragma unroll
        for (int r = 0; r < 16; ++r) acc[r] = wave_reduce_add(acc[r]);
        if (lane == 0) {
            #pragma unroll
            for (int r = 0; r < 16; ++r) {
                int row = rbase + h * 16 + r;
                int s   = s0 + row;
                float m = mask[b * SRC + s] ? NEG_INF : acc[r];
                sc[row] = m;
                scores_out[b * SRC + s] = m;
            }
        }
    }
    __syncthreads();

    // --- phase 2: local max and exp-sum over the 128 scores ---
    float myv = (tid < CHUNK) ? sc[tid] : NEG_INF;
    float wm = wave_reduce_max(myv);
    if (lane == 0) red[wid] = wm;
    __syncthreads();
    float lmax = fmaxf(fmaxf(red[0], red[1]), fmaxf(red[2], red[3]));

    float pe = 0.f;
    if (tid < CHUNK) {
        pe = (lmax == NEG_INF) ? 0.f : __expf(myv - lmax);
        pw[tid] = pe;
    }
    float ws = wave_reduce_add(pe);
    if (lane == 0) red[4 + wid] = ws;
    __syncthreads();
    if (tid == 0) {
        lmax_arr[b * NCHUNK + ch] = lmax;
        lsum_arr[b * NCHUNK + ch] = red[4] + red[5] + red[6] + red[7];
    }

    // --- phase 3: partial context (values chunk) ---
    const float4* v4 = (const float4*)(values + ((size_t)b * SRC + s0) * HIDDEN);
    float4 acc = {0.f, 0.f, 0.f, 0.f};
    #pragma unroll 4
    for (int i = 0; i < CHUNK; ++i) {
        float  w = pw[i];
        float4 v = ntload4(v4 + (size_t)i * 256 + tid);
        acc.x += w * v.x; acc.y += w * v.y; acc.z += w * v.z; acc.w += w * v.w;
    }
    ((float4*)(part + (size_t)(b * NCHUNK + ch) * HIDDEN))[tid] = acc;
}

// ---------- K3: combine partials -> ctx; normalize scores -> attn ----------
// grid (BATCH, 5): y==0 ctx reduce; y=1..4 attn quarters.
__global__ __launch_bounds__(256) void k_combine(const float* __restrict__ part,
                                                 const float* __restrict__ lmax_arr,
                                                 const float* __restrict__ lsum_arr,
                                                 const float* __restrict__ scores,
                                                 float* __restrict__ ctx,
                                                 float* __restrict__ attn) {
    int b = blockIdx.x, y = blockIdx.y, tid = threadIdx.x;
    __shared__ float sm[NCHUNK], ss[NCHUNK];
    if (tid < NCHUNK) {
        sm[tid] = lmax_arr[b * NCHUNK + tid];
        ss[tid] = lsum_arr[b * NCHUNK + tid];
    }
    __syncthreads();

    float M = NEG_INF;
    #pragma unroll
    for (int c = 0; c < NCHUNK; ++c) M = fmaxf(M, sm[c]);
    float Sum = 0.f;
    #pragma unroll
    for (int c = 0; c < NCHUNK; ++c) {
        float e = (sm[c] == NEG_INF) ? 0.f : __expf(sm[c] - M);
        Sum += ss[c] * e;
    }
    float inv = 1.f / Sum;

    if (y == 0) {
        const float4* p4 = (const float4*)(part + (size_t)b * NCHUNK * HIDDEN);
        float4 acc = {0.f, 0.f, 0.f, 0.f};
        #pragma unroll
        for (int c = 0; c < NCHUNK; ++c) {
            float w = ((sm[c] == NEG_INF) ? 0.f : __expf(sm[c] - M)) * inv;
            float4 v = p4[c * 256 + tid];
            acc.x += w * v.x; acc.y += w * v.y; acc.z += w * v.z; acc.w += w * v.w;
        }
        ((float4*)(ctx + (size_t)b * HIDDEN))[tid] = acc;
    } else {
        // quarter size in float4 units: SRC/4 floats per quarter = SRC/16 float4
        int base = (y - 1) * (SRC / 16);
        const float4* s4 = (const float4*)(scores + (size_t)b * SRC);
        float4*       a4 = (float4*)(attn + (size_t)b * SRC);
        float4 v = s4[base + tid];
        float4 r;
        r.x = __expf(v.x - M) * inv;
        r.y = __expf(v.y - M) * inv;
        r.z = __expf(v.z - M) * inv;
        r.w = __expf(v.w - M) * inv;
        a4[base + tid] = r;
    }
}

// ---------- launch ----------
extern "C" void kernel_launch(void* const* d_in, const int* in_sizes, int n_in,
                              void* d_out, int out_size, void* d_ws, size_t ws_size,
                              hipStream_t stream) {
    const float* query  = (const float*)d_in[0];
    const float* keys   = (const float*)d_in[1];
    const float* values = (const float*)d_in[2];
    const int*   mask   = (const int*)d_in[3];
    const float* W      = (const float*)d_in[4];

    float* ctx  = (float*)d_out;                  // (32, 1024)
    float* attn = (float*)d_out + BATCH * HIDDEN; // (32, 4096)

    float* proj   = (float*)d_ws;                       // 32768 f32
    float* scores = proj + BATCH * HIDDEN;              // 131072 f32
    float* part   = scores + BATCH * SRC;               // 4 MB
    float* lmax   = part + (size_t)BATCH * NCHUNK * HIDDEN;
    float* lsum   = lmax + BATCH * NCHUNK;

    k_proj   <<<dim3(BATCH * HIDDEN / 256), 256, 0, stream>>>(query, W, proj);
    k_fused  <<<dim3(BATCH, NCHUNK),        256, 0, stream>>>(keys, values, proj, mask,
                                                              scores, part, lmax, lsum);
    k_combine<<<dim3(BATCH, 5),             256, 0, stream>>>(part, lmax, lsum, scores,
                                                              ctx, attn);
}

// Round 6
// 116.022 us; speedup vs baseline: 2.2550x; 1.8438x over previous
//
#include <hip/hip_runtime.h>

constexpr int HIDDEN = 1024;
constexpr int BATCH  = 32;
constexpr int SRC    = 4096;
constexpr int CHUNK  = 128;              // s-rows per fused block
constexpr int NCHUNK = SRC / CHUNK;      // 32

#define NEG_INF (-__builtin_inff())

// ---------- helpers ----------

typedef float floatx4 __attribute__((ext_vector_type(4)));

__device__ __forceinline__ float4 ntload4(const float4* p) {
    floatx4 v = __builtin_nontemporal_load((const floatx4*)p);
    return make_float4(v.x, v.y, v.z, v.w);
}

__device__ __forceinline__ float wave_reduce_add(float v) {
    #pragma unroll
    for (int off = 32; off > 0; off >>= 1)
        v += __shfl_down(v, off, 64);
    return v;
}

__device__ __forceinline__ float wave_reduce_max(float v) {
    #pragma unroll
    for (int off = 32; off > 0; off >>= 1)
        v = fmaxf(v, __shfl_down(v, off, 64));
    return v;
}

__device__ __forceinline__ float dot16(float4 a, float4 b, float4 c, float4 d,
                                       float4 q0, float4 q1, float4 q2, float4 q3) {
    return a.x*q0.x + a.y*q0.y + a.z*q0.z + a.w*q0.w
         + b.x*q1.x + b.y*q1.y + b.z*q1.z + b.w*q1.w
         + c.x*q2.x + c.y*q2.y + c.z*q2.z + c.w*q2.w
         + d.x*q3.x + d.y*q3.y + d.z*q3.z + d.w*q3.w;
}

// ---------- K1: proj[b,o] = sum_i query[b,i] * W[o,i] ----------
// thread-per-(b,o), b minor: W loads wave-uniform (broadcast), W read once.
__global__ __launch_bounds__(256) void k_proj(const float* __restrict__ query,
                                              const float* __restrict__ W,
                                              float* __restrict__ proj) {
    int g = blockIdx.x * 256 + threadIdx.x;
    int b = g & (BATCH - 1);
    int o = g >> 5;
    const float4* W4 = (const float4*)(W + (size_t)o * HIDDEN);
    const float4* Q4 = (const float4*)(query + (size_t)b * HIDDEN);
    float4 acc = {0.f, 0.f, 0.f, 0.f};
    #pragma unroll 8
    for (int i = 0; i < HIDDEN / 4; ++i) {
        float4 w = W4[i];
        float4 q = Q4[i];
        acc.x += w.x * q.x; acc.y += w.y * q.y;
        acc.z += w.z * q.z; acc.w += w.w * q.w;
    }
    proj[(size_t)b * HIDDEN + o] = acc.x + acc.y + acc.z + acc.w;
}

// ---------- K2 (fused): masked-skip scores + stats + compacted partial context ----
// grid (BATCH, NCHUNK), block 256 (4 waves x 32 rows each).
__global__ __launch_bounds__(256, 4) void k_fused(const float* __restrict__ keys,
                                                  const float* __restrict__ values,
                                                  const float* __restrict__ proj,
                                                  const int* __restrict__ mask,
                                                  float* __restrict__ scores_out,
                                                  float* __restrict__ part,
                                                  float* __restrict__ lmax_arr,
                                                  float* __restrict__ lsum_arr) {
    int b   = blockIdx.x;
    int ch  = blockIdx.y;
    int tid = threadIdx.x;
    int wid = tid >> 6, lane = tid & 63;

    __shared__ float sc[CHUNK];     // masked scores
    __shared__ float red[8];
    __shared__ int   wcnt[2];       // live counts per half-chunk
    __shared__ int   idxc[CHUNK];   // compacted live row indices
    __shared__ float pwc[CHUNK];    // compacted weights exp(s - lmax)

    const float4* p4 = (const float4*)(proj + (size_t)b * HIDDEN);
    float4 q0 = p4[lane], q1 = p4[lane + 64], q2 = p4[lane + 128], q3 = p4[lane + 192];
    int s0    = ch * CHUNK;
    int rbase = wid * 32;

    // mask bits for this wave's 32 rows (bit r == row rbase+r masked)
    int mrow = (lane < 32) ? mask[(size_t)b * SRC + s0 + rbase + lane] : 1;
    unsigned mbits = (unsigned)(__ballot(mrow != 0) & 0xffffffffull);

    // --- phase 1: scores, batched deferred reduction, masked rows skip loads ---
    #pragma unroll
    for (int h = 0; h < 2; ++h) {
        float acc[16];
        #pragma unroll 2
        for (int r = 0; r < 16; ++r) {
            int rr = h * 16 + r;
            if (!((mbits >> rr) & 1)) {
                const float4* krow =
                    (const float4*)(keys + ((size_t)b * SRC + s0 + rbase + rr) * HIDDEN);
                float4 a = ntload4(krow + lane);
                float4 c = ntload4(krow + lane + 64);
                float4 d = ntload4(krow + lane + 128);
                float4 e = ntload4(krow + lane + 192);
                acc[r] = dot16(a, c, d, e, q0, q1, q2, q3);
            } else {
                acc[r] = NEG_INF;
            }
        }
        #pragma unroll
        for (int r = 0; r < 16; ++r)
            if (!((mbits >> (h * 16 + r)) & 1)) acc[r] = wave_reduce_add(acc[r]);
        if (lane == 0) {
            #pragma unroll
            for (int r = 0; r < 16; ++r) {
                int row = rbase + h * 16 + r;
                sc[row] = acc[r];
                scores_out[(size_t)b * SRC + s0 + row] = acc[r];
            }
        }
    }
    __syncthreads();

    // --- phase 2: local max, exp-sum, and deterministic compaction ---
    float myv = (tid < CHUNK) ? sc[tid] : NEG_INF;
    float wm = wave_reduce_max(myv);
    if (lane == 0) red[wid] = wm;
    __syncthreads();
    float lmax = fmaxf(fmaxf(red[0], red[1]), fmaxf(red[2], red[3]));

    float pe  = 0.f;
    bool live = false;
    if (tid < CHUNK) {
        pe   = (lmax == NEG_INF) ? 0.f : __expf(myv - lmax);
        live = (pe > 0.f);
    }
    // order-preserving ballot compaction within waves 0 and 1
    unsigned long long bal = __ballot(live);
    int pos  = __popcll(bal & ((1ull << lane) - 1ull));
    int wtot = __popcll(bal);
    if (wid < 2 && lane == 0) wcnt[wid] = wtot;

    float ws = wave_reduce_add(pe);
    if (lane == 0) red[4 + wid] = ws;
    __syncthreads();

    if (live) {
        int base = (wid == 1) ? wcnt[0] : 0;
        idxc[base + pos] = tid;
        pwc [base + pos] = pe;
    }
    if (tid == 0) {
        lmax_arr[b * NCHUNK + ch] = lmax;
        lsum_arr[b * NCHUNK + ch] = red[4] + red[5] + red[6] + red[7];
    }
    __syncthreads();
    int cnt = wcnt[0] + wcnt[1];

    // --- phase 3: partial context over live rows only (dense, branch-free) ---
    const float4* v4 = (const float4*)(values + ((size_t)b * SRC + s0) * HIDDEN);
    float4 acc = {0.f, 0.f, 0.f, 0.f};
    #pragma unroll 4
    for (int i = 0; i < cnt; ++i) {
        float  w   = pwc[i];
        int    row = idxc[i];
        float4 v   = ntload4(v4 + (size_t)row * 256 + tid);
        acc.x += w * v.x; acc.y += w * v.y; acc.z += w * v.z; acc.w += w * v.w;
    }
    ((float4*)(part + (size_t)(b * NCHUNK + ch) * HIDDEN))[tid] = acc;
}

// ---------- K3: combine partials -> ctx; normalize scores -> attn ----------
// grid (BATCH, 5): y==0 ctx reduce; y=1..4 attn quarters.
__global__ __launch_bounds__(256) void k_combine(const float* __restrict__ part,
                                                 const float* __restrict__ lmax_arr,
                                                 const float* __restrict__ lsum_arr,
                                                 const float* __restrict__ scores,
                                                 float* __restrict__ ctx,
                                                 float* __restrict__ attn) {
    int b = blockIdx.x, y = blockIdx.y, tid = threadIdx.x;
    __shared__ float sm[NCHUNK], ss[NCHUNK];
    if (tid < NCHUNK) {
        sm[tid] = lmax_arr[b * NCHUNK + tid];
        ss[tid] = lsum_arr[b * NCHUNK + tid];
    }
    __syncthreads();

    float M = NEG_INF;
    #pragma unroll
    for (int c = 0; c < NCHUNK; ++c) M = fmaxf(M, sm[c]);
    float Sum = 0.f;
    #pragma unroll
    for (int c = 0; c < NCHUNK; ++c) {
        float e = (sm[c] == NEG_INF) ? 0.f : __expf(sm[c] - M);
        Sum += ss[c] * e;
    }
    float inv = 1.f / Sum;

    if (y == 0) {
        const float4* p4 = (const float4*)(part + (size_t)b * NCHUNK * HIDDEN);
        float4 acc = {0.f, 0.f, 0.f, 0.f};
        #pragma unroll
        for (int c = 0; c < NCHUNK; ++c) {
            float w = ((sm[c] == NEG_INF) ? 0.f : __expf(sm[c] - M)) * inv;
            float4 v = p4[c * 256 + tid];
            acc.x += w * v.x; acc.y += w * v.y; acc.z += w * v.z; acc.w += w * v.w;
        }
        ((float4*)(ctx + (size_t)b * HIDDEN))[tid] = acc;
    } else {
        // quarter size in float4 units: SRC/4 floats per quarter = SRC/16 float4
        int base = (y - 1) * (SRC / 16);
        const float4* s4 = (const float4*)(scores + (size_t)b * SRC);
        float4*       a4 = (float4*)(attn + (size_t)b * SRC);
        float4 v = s4[base + tid];
        float4 r;
        r.x = __expf(v.x - M) * inv;
        r.y = __expf(v.y - M) * inv;
        r.z = __expf(v.z - M) * inv;
        r.w = __expf(v.w - M) * inv;
        a4[base + tid] = r;
    }
}

// ---------- launch ----------
extern "C" void kernel_launch(void* const* d_in, const int* in_sizes, int n_in,
                              void* d_out, int out_size, void* d_ws, size_t ws_size,
                              hipStream_t stream) {
    const float* query  = (const float*)d_in[0];
    const float* keys   = (const float*)d_in[1];
    const float* values = (const float*)d_in[2];
    const int*   mask   = (const int*)d_in[3];
    const float* W      = (const float*)d_in[4];

    float* ctx  = (float*)d_out;                  // (32, 1024)
    float* attn = (float*)d_out + BATCH * HIDDEN; // (32, 4096)

    float* proj   = (float*)d_ws;                       // 32768 f32
    float* scores = proj + BATCH * HIDDEN;              // 131072 f32
    float* part   = scores + BATCH * SRC;               // 4 MB
    float* lmax   = part + (size_t)BATCH * NCHUNK * HIDDEN;
    float* lsum   = lmax + BATCH * NCHUNK;

    k_proj   <<<dim3(BATCH * HIDDEN / 256), 256, 0, stream>>>(query, W, proj);
    k_fused  <<<dim3(BATCH, NCHUNK),        256, 0, stream>>>(keys, values, proj, mask,
                                                              scores, part, lmax, lsum);
    k_combine<<<dim3(BATCH, 5),             256, 0, stream>>>(part, lmax, lsum, scores,
                                                              ctx, attn);
}

// Round 7
// 101.260 us; speedup vs baseline: 2.5838x; 1.1458x over previous
//
#include <hip/hip_runtime.h>

constexpr int HIDDEN = 1024;
constexpr int BATCH  = 32;
constexpr int SRC    = 4096;
constexpr int CHUNK  = 128;              // s-rows per fused block
constexpr int NCHUNK = SRC / CHUNK;      // 32
constexpr int KSPLIT = 4;                // k_proj K-dimension split

#define NEG_INF (-__builtin_inff())

// ---------- helpers ----------

typedef float floatx4 __attribute__((ext_vector_type(4)));

__device__ __forceinline__ float4 ntload4(const float4* p) {
    floatx4 v = __builtin_nontemporal_load((const floatx4*)p);
    return make_float4(v.x, v.y, v.z, v.w);
}

__device__ __forceinline__ float wave_reduce_add(float v) {
    #pragma unroll
    for (int off = 32; off > 0; off >>= 1)
        v += __shfl_down(v, off, 64);
    return v;
}

__device__ __forceinline__ float wave_reduce_max(float v) {
    #pragma unroll
    for (int off = 32; off > 0; off >>= 1)
        v = fmaxf(v, __shfl_down(v, off, 64));
    return v;
}

__device__ __forceinline__ float dot16(float4 a, float4 b, float4 c, float4 d,
                                       float4 q0, float4 q1, float4 q2, float4 q3) {
    return a.x*q0.x + a.y*q0.y + a.z*q0.z + a.w*q0.w
         + b.x*q1.x + b.y*q1.y + b.z*q1.z + b.w*q1.w
         + c.x*q2.x + c.y*q2.y + c.z*q2.z + c.w*q2.w
         + d.x*q3.x + d.y*q3.y + d.z*q3.z + d.w*q3.w;
}

// ---------- K1: partial proj, K-split by 4 ----------
// pproj[z][b][o] = sum_{i in z-quarter} query[b,i] * W[o,i]
// grid (BATCH*HIDDEN/256, KSPLIT), block 256; b minor -> W loads wave-uniform.
__global__ __launch_bounds__(256) void k_proj(const float* __restrict__ query,
                                              const float* __restrict__ W,
                                              float* __restrict__ pproj) {
    int g = blockIdx.x * 256 + threadIdx.x;
    int b = g & (BATCH - 1);
    int o = g >> 5;
    int z = blockIdx.y;
    const float4* W4 = (const float4*)(W + (size_t)o * HIDDEN) + z * (HIDDEN / 4 / KSPLIT);
    const float4* Q4 = (const float4*)(query + (size_t)b * HIDDEN) + z * (HIDDEN / 4 / KSPLIT);
    float4 acc = {0.f, 0.f, 0.f, 0.f};
    #pragma unroll 8
    for (int i = 0; i < HIDDEN / 4 / KSPLIT; ++i) {
        float4 w = W4[i];
        float4 q = Q4[i];
        acc.x += w.x * q.x; acc.y += w.y * q.y;
        acc.z += w.z * q.z; acc.w += w.w * q.w;
    }
    pproj[((size_t)z * BATCH + b) * HIDDEN + o] = acc.x + acc.y + acc.z + acc.w;
}

// ---------- K2 (fused): masked-skip scores + stats + compacted partial context ----
// grid (BATCH, NCHUNK), block 256 (4 waves x 32 rows each).
__global__ __launch_bounds__(256, 4) void k_fused(const float* __restrict__ keys,
                                                  const float* __restrict__ values,
                                                  const float* __restrict__ pproj,
                                                  const int* __restrict__ mask,
                                                  float* __restrict__ scores_out,
                                                  float* __restrict__ part,
                                                  float* __restrict__ lmax_arr,
                                                  float* __restrict__ lsum_arr) {
    int b   = blockIdx.x;
    int ch  = blockIdx.y;
    int tid = threadIdx.x;
    int wid = tid >> 6, lane = tid & 63;

    __shared__ float sc[CHUNK];     // masked scores
    __shared__ float red[8];
    __shared__ int   wcnt[2];       // live counts per half-chunk
    __shared__ int   idxc[CHUNK];   // compacted live row indices
    __shared__ float pwc[CHUNK];    // compacted weights exp(s - lmax)

    // proj fragments = sum of the 4 K-split partials (L2-resident, 512 KB)
    float4 q0, q1, q2, q3;
    {
        const float4* pz0 = (const float4*)(pproj + ((size_t)0 * BATCH + b) * HIDDEN);
        const float4* pz1 = (const float4*)(pproj + ((size_t)1 * BATCH + b) * HIDDEN);
        const float4* pz2 = (const float4*)(pproj + ((size_t)2 * BATCH + b) * HIDDEN);
        const float4* pz3 = (const float4*)(pproj + ((size_t)3 * BATCH + b) * HIDDEN);
        #pragma unroll
        for (int f = 0; f < 4; ++f) {
            int idx = lane + f * 64;
            float4 a = pz0[idx], bb = pz1[idx], c = pz2[idx], d = pz3[idx];
            float4 s;
            s.x = (a.x + bb.x) + (c.x + d.x);
            s.y = (a.y + bb.y) + (c.y + d.y);
            s.z = (a.z + bb.z) + (c.z + d.z);
            s.w = (a.w + bb.w) + (c.w + d.w);
            if (f == 0) q0 = s; else if (f == 1) q1 = s; else if (f == 2) q2 = s; else q3 = s;
        }
    }
    int s0    = ch * CHUNK;
    int rbase = wid * 32;

    // mask bits for this wave's 32 rows (bit r == row rbase+r masked)
    int mrow = (lane < 32) ? mask[(size_t)b * SRC + s0 + rbase + lane] : 1;
    unsigned mbits = (unsigned)(__ballot(mrow != 0) & 0xffffffffull);

    // --- phase 1: scores, batched deferred reduction, masked rows skip loads ---
    #pragma unroll
    for (int h = 0; h < 2; ++h) {
        float acc[16];
        #pragma unroll 2
        for (int r = 0; r < 16; ++r) {
            int rr = h * 16 + r;
            if (!((mbits >> rr) & 1)) {
                const float4* krow =
                    (const float4*)(keys + ((size_t)b * SRC + s0 + rbase + rr) * HIDDEN);
                float4 a = ntload4(krow + lane);
                float4 c = ntload4(krow + lane + 64);
                float4 d = ntload4(krow + lane + 128);
                float4 e = ntload4(krow + lane + 192);
                acc[r] = dot16(a, c, d, e, q0, q1, q2, q3);
            } else {
                acc[r] = NEG_INF;
            }
        }
        #pragma unroll
        for (int r = 0; r < 16; ++r)
            if (!((mbits >> (h * 16 + r)) & 1)) acc[r] = wave_reduce_add(acc[r]);
        if (lane == 0) {
            #pragma unroll
            for (int r = 0; r < 16; ++r) {
                int row = rbase + h * 16 + r;
                sc[row] = acc[r];
                scores_out[(size_t)b * SRC + s0 + row] = acc[r];
            }
        }
    }
    __syncthreads();

    // --- phase 2: local max, exp-sum, and deterministic compaction ---
    float myv = (tid < CHUNK) ? sc[tid] : NEG_INF;
    float wm = wave_reduce_max(myv);
    if (lane == 0) red[wid] = wm;
    __syncthreads();
    float lmax = fmaxf(fmaxf(red[0], red[1]), fmaxf(red[2], red[3]));

    float pe  = 0.f;
    bool live = false;
    if (tid < CHUNK) {
        pe   = (lmax == NEG_INF) ? 0.f : __expf(myv - lmax);
        live = (pe > 0.f);
    }
    // order-preserving ballot compaction within waves 0 and 1
    unsigned long long bal = __ballot(live);
    int pos  = __popcll(bal & ((1ull << lane) - 1ull));
    int wtot = __popcll(bal);
    if (wid < 2 && lane == 0) wcnt[wid] = wtot;

    float ws = wave_reduce_add(pe);
    if (lane == 0) red[4 + wid] = ws;
    __syncthreads();

    if (live) {
        int base = (wid == 1) ? wcnt[0] : 0;
        idxc[base + pos] = tid;
        pwc [base + pos] = pe;
    }
    if (tid == 0) {
        lmax_arr[b * NCHUNK + ch] = lmax;
        lsum_arr[b * NCHUNK + ch] = red[4] + red[5] + red[6] + red[7];
    }
    __syncthreads();
    int cnt = wcnt[0] + wcnt[1];

    // --- phase 3: partial context over live rows only (dense, branch-free) ---
    const float4* v4 = (const float4*)(values + ((size_t)b * SRC + s0) * HIDDEN);
    float4 acc = {0.f, 0.f, 0.f, 0.f};
    #pragma unroll 4
    for (int i = 0; i < cnt; ++i) {
        float  w   = pwc[i];
        int    row = idxc[i];
        float4 v   = ntload4(v4 + (size_t)row * 256 + tid);
        acc.x += w * v.x; acc.y += w * v.y; acc.z += w * v.z; acc.w += w * v.w;
    }
    ((float4*)(part + (size_t)(b * NCHUNK + ch) * HIDDEN))[tid] = acc;
}

// ---------- K3: combine partials -> ctx; normalize scores -> attn ----------
// grid (BATCH, 5): y==0 ctx reduce; y=1..4 attn quarters.
__global__ __launch_bounds__(256) void k_combine(const float* __restrict__ part,
                                                 const float* __restrict__ lmax_arr,
                                                 const float* __restrict__ lsum_arr,
                                                 const float* __restrict__ scores,
                                                 float* __restrict__ ctx,
                                                 float* __restrict__ attn) {
    int b = blockIdx.x, y = blockIdx.y, tid = threadIdx.x;
    __shared__ float sm[NCHUNK], ss[NCHUNK];
    if (tid < NCHUNK) {
        sm[tid] = lmax_arr[b * NCHUNK + tid];
        ss[tid] = lsum_arr[b * NCHUNK + tid];
    }
    __syncthreads();

    float M = NEG_INF;
    #pragma unroll
    for (int c = 0; c < NCHUNK; ++c) M = fmaxf(M, sm[c]);
    float Sum = 0.f;
    #pragma unroll
    for (int c = 0; c < NCHUNK; ++c) {
        float e = (sm[c] == NEG_INF) ? 0.f : __expf(sm[c] - M);
        Sum += ss[c] * e;
    }
    float inv = 1.f / Sum;

    if (y == 0) {
        const float4* p4 = (const float4*)(part + (size_t)b * NCHUNK * HIDDEN);
        float4 acc = {0.f, 0.f, 0.f, 0.f};
        #pragma unroll
        for (int c = 0; c < NCHUNK; ++c) {
            float w = ((sm[c] == NEG_INF) ? 0.f : __expf(sm[c] - M)) * inv;
            float4 v = p4[c * 256 + tid];
            acc.x += w * v.x; acc.y += w * v.y; acc.z += w * v.z; acc.w += w * v.w;
        }
        ((float4*)(ctx + (size_t)b * HIDDEN))[tid] = acc;
    } else {
        // quarter size in float4 units: SRC/4 floats per quarter = SRC/16 float4
        int base = (y - 1) * (SRC / 16);
        const float4* s4 = (const float4*)(scores + (size_t)b * SRC);
        float4*       a4 = (float4*)(attn + (size_t)b * SRC);
        float4 v = s4[base + tid];
        float4 r;
        r.x = __expf(v.x - M) * inv;
        r.y = __expf(v.y - M) * inv;
        r.z = __expf(v.z - M) * inv;
        r.w = __expf(v.w - M) * inv;
        a4[base + tid] = r;
    }
}

// ---------- launch ----------
extern "C" void kernel_launch(void* const* d_in, const int* in_sizes, int n_in,
                              void* d_out, int out_size, void* d_ws, size_t ws_size,
                              hipStream_t stream) {
    const float* query  = (const float*)d_in[0];
    const float* keys   = (const float*)d_in[1];
    const float* values = (const float*)d_in[2];
    const int*   mask   = (const int*)d_in[3];
    const float* W      = (const float*)d_in[4];

    float* ctx  = (float*)d_out;                  // (32, 1024)
    float* attn = (float*)d_out + BATCH * HIDDEN; // (32, 4096)

    float* pproj  = (float*)d_ws;                         // KSPLIT*32*1024 f32 = 512 KB
    float* scores = pproj + (size_t)KSPLIT * BATCH * HIDDEN; // 131072 f32
    float* part   = scores + BATCH * SRC;                 // 4 MB
    float* lmax   = part + (size_t)BATCH * NCHUNK * HIDDEN;
    float* lsum   = lmax + BATCH * NCHUNK;

    k_proj   <<<dim3(BATCH * HIDDEN / 256, KSPLIT), 256, 0, stream>>>(query, W, pproj);
    k_fused  <<<dim3(BATCH, NCHUNK),                256, 0, stream>>>(keys, values, pproj, mask,
                                                                      scores, part, lmax, lsum);
    k_combine<<<dim3(BATCH, 5),                     256, 0, stream>>>(part, lmax, lsum, scores,
                                                                      ctx, attn);
}